// Round 3
// baseline (88.284 us; speedup 1.0000x reference)
//
#include <hip/hip_runtime.h>

#define N_SRC_C   100000
#define N_DST_C   50000
#define N_EDGES_C 800000
#define D_C       64
// h_neigh = (1-ALPHA)*HBar + ALPHA*mean   (stop_gradient identity in fwd)
#define ONE_MINUS_ALPHA 0.9f
#define ALPHA_C        0.1f

// ---------------------------------------------------------------------------
// Kernel 0: CSR row_ptr build from the sorted dst_idx.
// ---------------------------------------------------------------------------
__global__ __launch_bounds__(256) void build_rowptr_kernel(
    const int* __restrict__ dst_idx, int* __restrict__ row_ptr)
{
    const int e = blockIdx.x * 256 + threadIdx.x;
    if (e >= N_EDGES_C) return;
    const int d = dst_idx[e];
    const int p = (e == 0) ? -1 : dst_idx[e - 1];
    for (int n = p + 1; n <= d; ++n) row_ptr[n] = e;
    if (e == N_EDGES_C - 1) {
        for (int n = d + 1; n <= N_DST_C; ++n) row_ptr[n] = N_EDGES_C;
    }
}

// ---------------------------------------------------------------------------
// Kernel A: per-wave (64 lanes = 64 features) segment mean + CV blend.
// 8 independent accumulators keep 8 gather rows in flight.
// ---------------------------------------------------------------------------
__global__ __launch_bounds__(256) void sage_mean_kernel(
    const float* __restrict__ H_src,
    const float* __restrict__ HBar,
    const int*   __restrict__ src_idx,
    const int*   __restrict__ row_ptr,
    float*       __restrict__ h_neigh_out)  // [N_DST][64]
{
    const int wave = threadIdx.x >> 6;
    const int lane = threadIdx.x & 63;
    const int d = blockIdx.x * 4 + wave;
    if (d >= N_DST_C) return;

    const int seg_begin = row_ptr[d];
    const int seg_end   = row_ptr[d + 1];

    float a0 = 0.f, a1 = 0.f, a2 = 0.f, a3 = 0.f;
    float a4 = 0.f, a5 = 0.f, a6 = 0.f, a7 = 0.f;
    int e = seg_begin;
    for (; e + 8 <= seg_end; e += 8) {
        const int i0 = src_idx[e + 0];
        const int i1 = src_idx[e + 1];
        const int i2 = src_idx[e + 2];
        const int i3 = src_idx[e + 3];
        const int i4 = src_idx[e + 4];
        const int i5 = src_idx[e + 5];
        const int i6 = src_idx[e + 6];
        const int i7 = src_idx[e + 7];
        a0 += H_src[i0 * D_C + lane];
        a1 += H_src[i1 * D_C + lane];
        a2 += H_src[i2 * D_C + lane];
        a3 += H_src[i3 * D_C + lane];
        a4 += H_src[i4 * D_C + lane];
        a5 += H_src[i5 * D_C + lane];
        a6 += H_src[i6 * D_C + lane];
        a7 += H_src[i7 * D_C + lane];
    }
    for (; e + 4 <= seg_end; e += 4) {
        const int i0 = src_idx[e + 0];
        const int i1 = src_idx[e + 1];
        const int i2 = src_idx[e + 2];
        const int i3 = src_idx[e + 3];
        a0 += H_src[i0 * D_C + lane];
        a1 += H_src[i1 * D_C + lane];
        a2 += H_src[i2 * D_C + lane];
        a3 += H_src[i3 * D_C + lane];
    }
    for (; e < seg_end; ++e) {
        a0 += H_src[src_idx[e] * D_C + lane];
    }
    const float sum = ((a0 + a1) + (a2 + a3)) + ((a4 + a5) + (a6 + a7));
    const int cnt = seg_end - seg_begin;
    const float mean = (cnt > 0) ? (sum / (float)cnt) : 0.0f;

    const float hb = HBar[d * D_C + lane];
    h_neigh_out[d * D_C + lane] = ONE_MINUS_ALPHA * hb + ALPHA_C * mean;
}

// ---------------------------------------------------------------------------
// Kernel B: 64 nodes/block, 4 waves; wave q computes outputs [16q,16q+16) for
// all 64 nodes (node = lane). W and b are read with wave-uniform addresses
// (q forced uniform via readfirstlane) -> compiler emits s_load through the
// scalar/constant cache, and FMAs take W as the SGPR operand. NO LDS at all:
// the previous version burned ~30us broadcasting W through the LDS port at
// 16 useful bytes per ds_read_b128.
// ---------------------------------------------------------------------------
__global__ __launch_bounds__(256) void sage_linear_kernel(
    const float* __restrict__ H_dst,
    const float* __restrict__ h_neigh,   // output of kernel A
    const float* __restrict__ W,         // [64][128]
    const float* __restrict__ b,         // [64]
    float*       __restrict__ h_out)     // [N_DST][64]
{
    const int lane = threadIdx.x & 63;
    const int q    = __builtin_amdgcn_readfirstlane(threadIdx.x >> 6); // wave-uniform
    int node = blockIdx.x * 64 + lane;
    // clamp tail instead of returning: uniform control flow, duplicate
    // threads recompute identical values -> identical stores (benign).
    if (node > N_DST_C - 1) node = N_DST_C - 1;

    // x = [H_dst row | h_neigh row] in registers (static indices -> VGPRs)
    float x[128];
    #pragma unroll
    for (int k4 = 0; k4 < 16; ++k4) {
        const float4 v = *reinterpret_cast<const float4*>(&H_dst[node * 64 + k4 * 4]);
        x[k4 * 4 + 0] = v.x; x[k4 * 4 + 1] = v.y;
        x[k4 * 4 + 2] = v.z; x[k4 * 4 + 3] = v.w;
    }
    #pragma unroll
    for (int k4 = 0; k4 < 16; ++k4) {
        const float4 v = *reinterpret_cast<const float4*>(&h_neigh[node * 64 + k4 * 4]);
        x[64 + k4 * 4 + 0] = v.x; x[64 + k4 * 4 + 1] = v.y;
        x[64 + k4 * 4 + 2] = v.z; x[64 + k4 * 4 + 3] = v.w;
    }

    float acc[16];
    for (int oo = 0; oo < 16; ++oo) {
        const int o = q * 16 + oo;                       // wave-uniform
        const float* __restrict__ wrow = W + o * 128;    // uniform base -> s_load
        float p0 = 0.f, p1 = 0.f, p2 = 0.f, p3 = 0.f;
        #pragma unroll
        for (int k4 = 0; k4 < 32; ++k4) {
            p0 += wrow[k4 * 4 + 0] * x[k4 * 4 + 0];
            p1 += wrow[k4 * 4 + 1] * x[k4 * 4 + 1];
            p2 += wrow[k4 * 4 + 2] * x[k4 * 4 + 2];
            p3 += wrow[k4 * 4 + 3] * x[k4 * 4 + 3];
        }
        acc[oo] = fmaxf(b[o] + ((p0 + p1) + (p2 + p3)), 0.0f);
    }

    #pragma unroll
    for (int oo4 = 0; oo4 < 4; ++oo4) {
        float4 v;
        v.x = acc[oo4 * 4 + 0]; v.y = acc[oo4 * 4 + 1];
        v.z = acc[oo4 * 4 + 2]; v.w = acc[oo4 * 4 + 3];
        *reinterpret_cast<float4*>(&h_out[node * 64 + q * 16 + oo4 * 4]) = v;
    }
}

// ---------------------------------------------------------------------------
extern "C" void kernel_launch(void* const* d_in, const int* in_sizes, int n_in,
                              void* d_out, int out_size, void* d_ws, size_t ws_size,
                              hipStream_t stream) {
    const float* H_src   = (const float*)d_in[0];
    const float* H_dst   = (const float*)d_in[1];
    const float* HBar    = (const float*)d_in[2];
    const int*   src_idx = (const int*)d_in[3];
    const int*   dst_idx = (const int*)d_in[4];
    const float* W       = (const float*)d_in[5];
    const float* b       = (const float*)d_in[6];

    float* out     = (float*)d_out;
    float* h_out   = out;                            // [N_DST][64]
    float* hn_out  = out + (size_t)N_DST_C * D_C;    // [N_DST][64]

    int* row_ptr = (int*)d_ws;                       // (N_DST+1) ints = 200 KB

    hipLaunchKernelGGL(build_rowptr_kernel, dim3((N_EDGES_C + 255) / 256), dim3(256), 0, stream,
                       dst_idx, row_ptr);

    hipLaunchKernelGGL(sage_mean_kernel, dim3(N_DST_C / 4), dim3(256), 0, stream,
                       H_src, HBar, src_idx, row_ptr, hn_out);

    hipLaunchKernelGGL(sage_linear_kernel, dim3((N_DST_C + 63) / 64), dim3(256), 0, stream,
                       H_dst, hn_out, W, b, h_out);
}

// Round 4
// 85.268 us; speedup vs baseline: 1.0354x; 1.0354x over previous
//
#include <hip/hip_runtime.h>

#define N_SRC_C   100000
#define N_DST_C   50000
#define N_EDGES_C 800000
#define D_C       64
// h_neigh = (1-ALPHA)*HBar + ALPHA*mean   (stop_gradient identity in fwd)
#define ONE_MINUS_ALPHA 0.9f
#define ALPHA_C        0.1f

// ---------------------------------------------------------------------------
// Kernel 0: CSR row_ptr build from the sorted dst_idx.
// ---------------------------------------------------------------------------
__global__ __launch_bounds__(256) void build_rowptr_kernel(
    const int* __restrict__ dst_idx, int* __restrict__ row_ptr)
{
    const int e = blockIdx.x * 256 + threadIdx.x;
    if (e >= N_EDGES_C) return;
    const int d = dst_idx[e];
    const int p = (e == 0) ? -1 : dst_idx[e - 1];
    for (int n = p + 1; n <= d; ++n) row_ptr[n] = e;
    if (e == N_EDGES_C - 1) {
        for (int n = d + 1; n <= N_DST_C; ++n) row_ptr[n] = N_EDGES_C;
    }
}

// ---------------------------------------------------------------------------
// Kernel A: per-wave segment mean + CV blend, float4-lane remap.
// lane = g*16 + c: group g (0..3) gathers edge e+g, chunk c covers features
// [4c,4c+4). One wave-load instruction fetches FOUR edge rows (4x fewer VMEM
// instructions than lane=feature); 4 predicated load groups -> 16 edges in
// flight. Cross-group finish: shfl_xor over lanes ^16, ^32.
// ---------------------------------------------------------------------------
__global__ __launch_bounds__(256) void sage_mean_kernel(
    const float* __restrict__ H_src,
    const float* __restrict__ HBar,
    const int*   __restrict__ src_idx,
    const int*   __restrict__ row_ptr,
    float*       __restrict__ h_neigh_out)  // [N_DST][64]
{
    const int wave = threadIdx.x >> 6;
    const int lane = threadIdx.x & 63;
    const int g    = lane >> 4;      // edge sub-group 0..3
    const int c    = lane & 15;      // feature chunk: floats [4c, 4c+4)
    const int d = blockIdx.x * 4 + wave;
    if (d >= N_DST_C) return;

    const int s0 = row_ptr[d];
    const int s1 = row_ptr[d + 1];

    float4 A = {0.f, 0.f, 0.f, 0.f};
    float4 B = {0.f, 0.f, 0.f, 0.f};
    float4 C = {0.f, 0.f, 0.f, 0.f};
    float4 Dd = {0.f, 0.f, 0.f, 0.f};

    for (int e = s0; e < s1; e += 16) {
        const int e0 = e + g, e1 = e + 4 + g, e2 = e + 8 + g, e3 = e + 12 + g;
        if (e0 < s1) {
            const float4 v = *reinterpret_cast<const float4*>(
                H_src + (size_t)src_idx[e0] * D_C + c * 4);
            A.x += v.x; A.y += v.y; A.z += v.z; A.w += v.w;
        }
        if (e1 < s1) {
            const float4 v = *reinterpret_cast<const float4*>(
                H_src + (size_t)src_idx[e1] * D_C + c * 4);
            B.x += v.x; B.y += v.y; B.z += v.z; B.w += v.w;
        }
        if (e2 < s1) {
            const float4 v = *reinterpret_cast<const float4*>(
                H_src + (size_t)src_idx[e2] * D_C + c * 4);
            C.x += v.x; C.y += v.y; C.z += v.z; C.w += v.w;
        }
        if (e3 < s1) {
            const float4 v = *reinterpret_cast<const float4*>(
                H_src + (size_t)src_idx[e3] * D_C + c * 4);
            Dd.x += v.x; Dd.y += v.y; Dd.z += v.z; Dd.w += v.w;
        }
    }
    float4 S;
    S.x = (A.x + B.x) + (C.x + Dd.x);
    S.y = (A.y + B.y) + (C.y + Dd.y);
    S.z = (A.z + B.z) + (C.z + Dd.z);
    S.w = (A.w + B.w) + (C.w + Dd.w);

    // reduce across the 4 edge-groups (lane ^16, ^32)
    S.x += __shfl_xor(S.x, 16); S.y += __shfl_xor(S.y, 16);
    S.z += __shfl_xor(S.z, 16); S.w += __shfl_xor(S.w, 16);
    S.x += __shfl_xor(S.x, 32); S.y += __shfl_xor(S.y, 32);
    S.z += __shfl_xor(S.z, 32); S.w += __shfl_xor(S.w, 32);

    const int cnt = s1 - s0;
    const float inv = (cnt > 0) ? (ALPHA_C / (float)cnt) : 0.0f;

    if (g == 0) {
        const float4 hb = *reinterpret_cast<const float4*>(HBar + (size_t)d * D_C + c * 4);
        float4 o;
        o.x = ONE_MINUS_ALPHA * hb.x + S.x * inv;
        o.y = ONE_MINUS_ALPHA * hb.y + S.y * inv;
        o.z = ONE_MINUS_ALPHA * hb.z + S.z * inv;
        o.w = ONE_MINUS_ALPHA * hb.w + S.w * inv;
        *reinterpret_cast<float4*>(h_neigh_out + (size_t)d * D_C + c * 4) = o;
    }
}

// ---------------------------------------------------------------------------
// Kernel B: 512 threads = 8 waves per block; 64 nodes/block (node = lane).
// Wave q computes outputs [8q, 8q+8). k-OUTER loop: per float4 x-chunk,
// 8 accumulators each take 4 FMAs -> every x load amortized over 64 FLOPs,
// only ~12 live VGPRs of state. W/b addresses are wave-uniform
// (readfirstlane) -> scalar loads through the constant cache, no LDS.
// ---------------------------------------------------------------------------
__global__ __launch_bounds__(512) void sage_linear_kernel(
    const float* __restrict__ H_dst,
    const float* __restrict__ h_neigh,   // output of kernel A
    const float* __restrict__ W,         // [64][128]
    const float* __restrict__ b,         // [64]
    float*       __restrict__ h_out)     // [N_DST][64]
{
    const int lane = threadIdx.x & 63;
    const int q    = __builtin_amdgcn_readfirstlane((int)(threadIdx.x >> 6)); // 0..7
    int node = blockIdx.x * 64 + lane;
    if (node > N_DST_C - 1) node = N_DST_C - 1;   // tail: duplicate identical work

    float acc[8];
    #pragma unroll
    for (int oo = 0; oo < 8; ++oo) acc[oo] = b[q * 8 + oo];

    const float* __restrict__ xd = H_dst   + (size_t)node * D_C;
    const float* __restrict__ xn = h_neigh + (size_t)node * D_C;

    #pragma unroll
    for (int h = 0; h < 2; ++h) {
        const float* __restrict__ xr = (h == 0) ? xd : xn;
        #pragma unroll 4
        for (int kc = 0; kc < 16; ++kc) {
            const float4 xv = *reinterpret_cast<const float4*>(xr + kc * 4);
            #pragma unroll
            for (int oo = 0; oo < 8; ++oo) {
                const float4 wv = *reinterpret_cast<const float4*>(
                    W + (q * 8 + oo) * 128 + h * 64 + kc * 4);   // uniform -> s_load
                acc[oo] = fmaf(wv.x, xv.x, acc[oo]);
                acc[oo] = fmaf(wv.y, xv.y, acc[oo]);
                acc[oo] = fmaf(wv.z, xv.z, acc[oo]);
                acc[oo] = fmaf(wv.w, xv.w, acc[oo]);
            }
        }
    }

    #pragma unroll
    for (int j = 0; j < 2; ++j) {
        float4 v;
        v.x = fmaxf(acc[j * 4 + 0], 0.0f);
        v.y = fmaxf(acc[j * 4 + 1], 0.0f);
        v.z = fmaxf(acc[j * 4 + 2], 0.0f);
        v.w = fmaxf(acc[j * 4 + 3], 0.0f);
        *reinterpret_cast<float4*>(&h_out[(size_t)node * D_C + q * 8 + j * 4]) = v;
    }
}

// ---------------------------------------------------------------------------
extern "C" void kernel_launch(void* const* d_in, const int* in_sizes, int n_in,
                              void* d_out, int out_size, void* d_ws, size_t ws_size,
                              hipStream_t stream) {
    const float* H_src   = (const float*)d_in[0];
    const float* H_dst   = (const float*)d_in[1];
    const float* HBar    = (const float*)d_in[2];
    const int*   src_idx = (const int*)d_in[3];
    const int*   dst_idx = (const int*)d_in[4];
    const float* W       = (const float*)d_in[5];
    const float* b       = (const float*)d_in[6];

    float* out     = (float*)d_out;
    float* h_out   = out;                            // [N_DST][64]
    float* hn_out  = out + (size_t)N_DST_C * D_C;    // [N_DST][64]

    int* row_ptr = (int*)d_ws;                       // (N_DST+1) ints = 200 KB

    hipLaunchKernelGGL(build_rowptr_kernel, dim3((N_EDGES_C + 255) / 256), dim3(256), 0, stream,
                       dst_idx, row_ptr);

    hipLaunchKernelGGL(sage_mean_kernel, dim3(N_DST_C / 4), dim3(256), 0, stream,
                       H_src, HBar, src_idx, row_ptr, hn_out);

    hipLaunchKernelGGL(sage_linear_kernel, dim3((N_DST_C + 63) / 64), dim3(512), 0, stream,
                       H_dst, hn_out, W, b, h_out);
}

// Round 5
// 79.570 us; speedup vs baseline: 1.1095x; 1.0716x over previous
//
#include <hip/hip_runtime.h>

#define N_SRC_C   100000
#define N_DST_C   50000
#define N_EDGES_C 800000
#define D_C       64
// h_neigh = (1-ALPHA)*HBar + ALPHA*mean   (stop_gradient identity in fwd)
#define ONE_MINUS_ALPHA 0.9f
#define ALPHA_C        0.1f

// ---------------------------------------------------------------------------
// Kernel W: transpose W [64][128] -> WT [128][64] (k-major) so the linear
// kernel's per-lane W-register fill is coalesced (lane = output).
// ---------------------------------------------------------------------------
__global__ __launch_bounds__(256) void transpose_w_kernel(
    const float* __restrict__ W, float* __restrict__ WT)
{
    const int i = blockIdx.x * 256 + threadIdx.x;   // i = o*128 + k
    if (i >= 64 * 128) return;
    const int o = i >> 7, k = i & 127;
    WT[k * 64 + o] = W[i];
}

// ---------------------------------------------------------------------------
// Kernel C: convert H_src f32 -> bf16 (RNE). Halves the random-gather bytes:
// a 64-feature row becomes 128B = one cache line, and the whole table
// (12.8MB) fits in aggregate L2.
// ---------------------------------------------------------------------------
__global__ __launch_bounds__(256) void convert_bf16_kernel(
    const float* __restrict__ H_src, ushort* __restrict__ Hb)
{
    const int i = blockIdx.x * 256 + threadIdx.x;   // one float4 -> one ushort4
    if (i >= N_SRC_C * D_C / 4) return;
    const float4 v = reinterpret_cast<const float4*>(H_src)[i];
    ushort4 o;
    uint u;
    u = __float_as_uint(v.x); o.x = (ushort)((u + 0x7fffu + ((u >> 16) & 1u)) >> 16);
    u = __float_as_uint(v.y); o.y = (ushort)((u + 0x7fffu + ((u >> 16) & 1u)) >> 16);
    u = __float_as_uint(v.z); o.z = (ushort)((u + 0x7fffu + ((u >> 16) & 1u)) >> 16);
    u = __float_as_uint(v.w); o.w = (ushort)((u + 0x7fffu + ((u >> 16) & 1u)) >> 16);
    reinterpret_cast<ushort4*>(Hb)[i] = o;
}

// ---------------------------------------------------------------------------
// Kernel 0: CSR row_ptr build from the sorted dst_idx.
// ---------------------------------------------------------------------------
__global__ __launch_bounds__(256) void build_rowptr_kernel(
    const int* __restrict__ dst_idx, int* __restrict__ row_ptr)
{
    const int e = blockIdx.x * 256 + threadIdx.x;
    if (e >= N_EDGES_C) return;
    const int d = dst_idx[e];
    const int p = (e == 0) ? -1 : dst_idx[e - 1];
    for (int n = p + 1; n <= d; ++n) row_ptr[n] = e;
    if (e == N_EDGES_C - 1) {
        for (int n = d + 1; n <= N_DST_C; ++n) row_ptr[n] = N_EDGES_C;
    }
}

// ---------------------------------------------------------------------------
// Kernel A: per-wave segment mean + CV blend, bf16 gather.
// lane = g*16 + c: group g (0..3) gathers edge e+g's bf16 chunk [4c,4c+4)
// (8B). One wave-load touches 4 rows x 128B = 4 cache lines. Accumulate f32;
// cross-group finish via shfl_xor ^16, ^32.
// ---------------------------------------------------------------------------
__global__ __launch_bounds__(256) void sage_mean_kernel(
    const ushort* __restrict__ Hb,       // bf16 H_src [N_SRC][64]
    const float*  __restrict__ HBar,
    const int*    __restrict__ src_idx,
    const int*    __restrict__ row_ptr,
    float*        __restrict__ h_neigh_out)  // [N_DST][64]
{
    const int wave = threadIdx.x >> 6;
    const int lane = threadIdx.x & 63;
    const int g    = lane >> 4;      // edge sub-group 0..3
    const int c    = lane & 15;      // feature chunk: floats [4c, 4c+4)
    const int d = blockIdx.x * 4 + wave;
    if (d >= N_DST_C) return;

    const int s0 = row_ptr[d];
    const int s1 = row_ptr[d + 1];

    float4 A = {0.f, 0.f, 0.f, 0.f};
    float4 B = {0.f, 0.f, 0.f, 0.f};
    float4 C = {0.f, 0.f, 0.f, 0.f};
    float4 Dd = {0.f, 0.f, 0.f, 0.f};

    for (int e = s0; e < s1; e += 16) {
        const int e0 = e + g, e1 = e + 4 + g, e2 = e + 8 + g, e3 = e + 12 + g;
        if (e0 < s1) {
            const uint2 p = *reinterpret_cast<const uint2*>(
                Hb + (size_t)src_idx[e0] * D_C + c * 4);
            A.x += __uint_as_float(p.x << 16);
            A.y += __uint_as_float(p.x & 0xffff0000u);
            A.z += __uint_as_float(p.y << 16);
            A.w += __uint_as_float(p.y & 0xffff0000u);
        }
        if (e1 < s1) {
            const uint2 p = *reinterpret_cast<const uint2*>(
                Hb + (size_t)src_idx[e1] * D_C + c * 4);
            B.x += __uint_as_float(p.x << 16);
            B.y += __uint_as_float(p.x & 0xffff0000u);
            B.z += __uint_as_float(p.y << 16);
            B.w += __uint_as_float(p.y & 0xffff0000u);
        }
        if (e2 < s1) {
            const uint2 p = *reinterpret_cast<const uint2*>(
                Hb + (size_t)src_idx[e2] * D_C + c * 4);
            C.x += __uint_as_float(p.x << 16);
            C.y += __uint_as_float(p.x & 0xffff0000u);
            C.z += __uint_as_float(p.y << 16);
            C.w += __uint_as_float(p.y & 0xffff0000u);
        }
        if (e3 < s1) {
            const uint2 p = *reinterpret_cast<const uint2*>(
                Hb + (size_t)src_idx[e3] * D_C + c * 4);
            Dd.x += __uint_as_float(p.x << 16);
            Dd.y += __uint_as_float(p.x & 0xffff0000u);
            Dd.z += __uint_as_float(p.y << 16);
            Dd.w += __uint_as_float(p.y & 0xffff0000u);
        }
    }
    float4 S;
    S.x = (A.x + B.x) + (C.x + Dd.x);
    S.y = (A.y + B.y) + (C.y + Dd.y);
    S.z = (A.z + B.z) + (C.z + Dd.z);
    S.w = (A.w + B.w) + (C.w + Dd.w);

    S.x += __shfl_xor(S.x, 16); S.y += __shfl_xor(S.y, 16);
    S.z += __shfl_xor(S.z, 16); S.w += __shfl_xor(S.w, 16);
    S.x += __shfl_xor(S.x, 32); S.y += __shfl_xor(S.y, 32);
    S.z += __shfl_xor(S.z, 32); S.w += __shfl_xor(S.w, 32);

    const int cnt = s1 - s0;
    const float inv = (cnt > 0) ? (ALPHA_C / (float)cnt) : 0.0f;

    if (g == 0) {
        const float4 hb = *reinterpret_cast<const float4*>(HBar + (size_t)d * D_C + c * 4);
        float4 o;
        o.x = ONE_MINUS_ALPHA * hb.x + S.x * inv;
        o.y = ONE_MINUS_ALPHA * hb.y + S.y * inv;
        o.z = ONE_MINUS_ALPHA * hb.z + S.z * inv;
        o.w = ONE_MINUS_ALPHA * hb.w + S.w * inv;
        *reinterpret_cast<float4*>(h_neigh_out + (size_t)d * D_C + c * 4) = o;
    }
}

// ---------------------------------------------------------------------------
// Kernel B: lane = output o. Each lane holds W row o (128 f32) in VGPRs,
// filled coalesced from the k-major WT. Waves grid-stride over nodes; the
// x-row address is wave-uniform (readfirstlane) -> x comes through the
// SCALAR pipe (s_load broadcast, built for this) and each FMA is
// v_fmac(acc, s_x, v_w). Store: 64 lanes x 4B contiguous.
// ---------------------------------------------------------------------------
__global__ __launch_bounds__(256) void sage_linear_kernel(
    const float* __restrict__ H_dst,
    const float* __restrict__ h_neigh,
    const float* __restrict__ WT,        // [128][64] k-major
    const float* __restrict__ b,
    float*       __restrict__ h_out)     // [N_DST][64]
{
    const int lane = threadIdx.x & 63;
    const int wid  = blockIdx.x * 4 + (threadIdx.x >> 6);
    const int nw   = gridDim.x * 4;

    float wreg[128];
    #pragma unroll
    for (int k = 0; k < 128; ++k) wreg[k] = WT[k * 64 + lane];  // coalesced
    const float bias = b[lane];

    for (int node = wid; node < N_DST_C; node += nw) {
        const int un = __builtin_amdgcn_readfirstlane(node);
        const float* __restrict__ xd = H_dst   + (size_t)un * D_C;
        const float* __restrict__ xn = h_neigh + (size_t)un * D_C;

        float a0 = 0.f, a1 = 0.f, a2 = 0.f, a3 = 0.f;
        #pragma unroll
        for (int k = 0; k < 16; ++k) {
            a0 = fmaf(wreg[k * 4 + 0], xd[k * 4 + 0], a0);
            a1 = fmaf(wreg[k * 4 + 1], xd[k * 4 + 1], a1);
            a2 = fmaf(wreg[k * 4 + 2], xd[k * 4 + 2], a2);
            a3 = fmaf(wreg[k * 4 + 3], xd[k * 4 + 3], a3);
        }
        #pragma unroll
        for (int k = 0; k < 16; ++k) {
            a0 = fmaf(wreg[64 + k * 4 + 0], xn[k * 4 + 0], a0);
            a1 = fmaf(wreg[64 + k * 4 + 1], xn[k * 4 + 1], a1);
            a2 = fmaf(wreg[64 + k * 4 + 2], xn[k * 4 + 2], a2);
            a3 = fmaf(wreg[64 + k * 4 + 3], xn[k * 4 + 3], a3);
        }
        h_out[(size_t)un * D_C + lane] = fmaxf(bias + ((a0 + a1) + (a2 + a3)), 0.0f);
    }
}

// ---------------------------------------------------------------------------
extern "C" void kernel_launch(void* const* d_in, const int* in_sizes, int n_in,
                              void* d_out, int out_size, void* d_ws, size_t ws_size,
                              hipStream_t stream) {
    const float* H_src   = (const float*)d_in[0];
    const float* H_dst   = (const float*)d_in[1];
    const float* HBar    = (const float*)d_in[2];
    const int*   src_idx = (const int*)d_in[3];
    const int*   dst_idx = (const int*)d_in[4];
    const float* W       = (const float*)d_in[5];
    const float* b       = (const float*)d_in[6];

    float* out    = (float*)d_out;
    float* h_out  = out;                             // [N_DST][64] (written LAST)
    float* hn_out = out + (size_t)N_DST_C * D_C;     // [N_DST][64]

    // ws: row_ptr (200KB) then WT (32KB). bf16 H_src (12.8MB) borrows the
    // h-region of d_out, which is free until the final linear kernel.
    int*    row_ptr = (int*)d_ws;
    float*  WT      = (float*)((char*)d_ws + (256 << 10));
    ushort* Hb      = (ushort*)h_out;                // exactly 12.8MB available

    hipLaunchKernelGGL(transpose_w_kernel, dim3(32), dim3(256), 0, stream, W, WT);

    hipLaunchKernelGGL(convert_bf16_kernel, dim3((N_SRC_C * D_C / 4 + 255) / 256), dim3(256),
                       0, stream, H_src, Hb);

    hipLaunchKernelGGL(build_rowptr_kernel, dim3((N_EDGES_C + 255) / 256), dim3(256), 0, stream,
                       dst_idx, row_ptr);

    hipLaunchKernelGGL(sage_mean_kernel, dim3(N_DST_C / 4), dim3(256), 0, stream,
                       Hb, HBar, src_idx, row_ptr, hn_out);

    // 768 blocks = 3072 waves (~3/SIMD at ~140 VGPR), grid-stride over nodes.
    hipLaunchKernelGGL(sage_linear_kernel, dim3(768), dim3(256), 0, stream,
                       H_dst, hn_out, WT, b, h_out);
}

// Round 6
// 60.963 us; speedup vs baseline: 1.4481x; 1.3052x over previous
//
#include <hip/hip_runtime.h>

#define N_SRC_C   100000
#define N_DST_C   50000
#define N_EDGES_C 800000
#define D_C       64
// h_neigh = (1-ALPHA)*HBar + ALPHA*mean   (stop_gradient identity in fwd)
#define ONE_MINUS_ALPHA 0.9f
#define ALPHA_C        0.1f

#define CONV_ITEMS (N_SRC_C * D_C / 4)          // 1,600,000 float4 -> ushort4
#define PREP_BLOCKS ((CONV_ITEMS + 255) / 256)  // 6250

// ---------------------------------------------------------------------------
// Fused prep kernel: (1) H_src f32 -> bf16 table, (2) CSR row_ptr from sorted
// dst_idx, (3) W transpose to k-major. Index-range tasks in one launch:
// saves two kernel launches and overlaps three independent memory streams.
// ---------------------------------------------------------------------------
__global__ __launch_bounds__(256) void prep_kernel(
    const float* __restrict__ H_src, ushort* __restrict__ Hb,
    const int* __restrict__ dst_idx, int* __restrict__ row_ptr,
    const float* __restrict__ W, float* __restrict__ WT)
{
    const int t = blockIdx.x * 256 + threadIdx.x;

    if (t < CONV_ITEMS) {                       // bf16 convert (RNE)
        const float4 v = reinterpret_cast<const float4*>(H_src)[t];
        ushort4 o; uint u;
        u = __float_as_uint(v.x); o.x = (ushort)((u + 0x7fffu + ((u >> 16) & 1u)) >> 16);
        u = __float_as_uint(v.y); o.y = (ushort)((u + 0x7fffu + ((u >> 16) & 1u)) >> 16);
        u = __float_as_uint(v.z); o.z = (ushort)((u + 0x7fffu + ((u >> 16) & 1u)) >> 16);
        u = __float_as_uint(v.w); o.w = (ushort)((u + 0x7fffu + ((u >> 16) & 1u)) >> 16);
        reinterpret_cast<ushort4*>(Hb)[t] = o;
    }

    if (t < N_EDGES_C) {                        // CSR row_ptr
        const int d = dst_idx[t];
        const int p = (t == 0) ? -1 : dst_idx[t - 1];
        for (int n = p + 1; n <= d; ++n) row_ptr[n] = t;
        if (t == N_EDGES_C - 1) {
            for (int n = d + 1; n <= N_DST_C; ++n) row_ptr[n] = N_EDGES_C;
        }
    }

    if (t < 64 * 128) {                         // W[64][128] -> WT[128][64]
        const int o = t >> 7, k = t & 127;
        WT[k * 64 + o] = W[t];
    }
}

// ---------------------------------------------------------------------------
// Mean kernel, high-MLP layout: 8 nodes per wave. Group g (8 lanes) owns node
// wave*8+g; lane c owns features [8c, 8c+8). One gather instruction fetches
// EIGHT 128B bf16 rows (vs 4 before). Edge indices are preloaded coalesced
// (lane c reads src_idx[e+c]) one iteration AHEAD and distributed via shfl,
// so gathers issue back-to-back with no memory dependency in front.
// No cross-lane reduction: each lane owns its features outright.
// ---------------------------------------------------------------------------
__global__ __launch_bounds__(256) void sage_mean_kernel(
    const ushort* __restrict__ Hb,       // bf16 H_src [N_SRC][64]
    const float*  __restrict__ HBar,
    const int*    __restrict__ src_idx,
    const int*    __restrict__ row_ptr,
    float*        __restrict__ h_neigh_out)  // [N_DST][64]
{
    const int lane = threadIdx.x & 63;
    const int g    = lane >> 3;                        // node slot 0..7
    const int c    = lane & 7;                         // feature chunk
    const int wave = blockIdx.x * 4 + (threadIdx.x >> 6);
    const int node = wave * 8 + g;
    if (node >= N_DST_C) return;                       // whole-wave exit only

    const int s0 = row_ptr[node];
    const int s1 = row_ptr[node + 1];

    float acc[8];
    #pragma unroll
    for (int i = 0; i < 8; ++i) acc[i] = 0.f;

    // software-pipelined index preload: lane c holds idx of edge e+c
    int myidx = 0;
    if (s0 < s1) {
        const int ec = s0 + c;
        myidx = src_idx[ec < s1 ? ec : s1 - 1];
    }

    for (int e = s0; e < s1; e += 8) {
        int nextidx = 0;
        if (e + 8 < s1) {
            const int ec = e + 8 + c;
            nextidx = src_idx[ec < s1 ? ec : s1 - 1];
        }
        #pragma unroll
        for (int j = 0; j < 8; ++j) {
            const int ij = __shfl(myidx, g * 8 + j);
            if (e + j < s1) {
                const uint4 p = *reinterpret_cast<const uint4*>(
                    Hb + (size_t)ij * D_C + c * 8);
                acc[0] += __uint_as_float(p.x << 16);
                acc[1] += __uint_as_float(p.x & 0xffff0000u);
                acc[2] += __uint_as_float(p.y << 16);
                acc[3] += __uint_as_float(p.y & 0xffff0000u);
                acc[4] += __uint_as_float(p.z << 16);
                acc[5] += __uint_as_float(p.z & 0xffff0000u);
                acc[6] += __uint_as_float(p.w << 16);
                acc[7] += __uint_as_float(p.w & 0xffff0000u);
            }
        }
        myidx = nextidx;
    }

    const int cnt = s1 - s0;
    const float inv = (cnt > 0) ? (ALPHA_C / (float)cnt) : 0.0f;

    const size_t base = (size_t)node * D_C + c * 8;
    const float4 hb0 = *reinterpret_cast<const float4*>(HBar + base);
    const float4 hb1 = *reinterpret_cast<const float4*>(HBar + base + 4);
    float4 o0, o1;
    o0.x = ONE_MINUS_ALPHA * hb0.x + acc[0] * inv;
    o0.y = ONE_MINUS_ALPHA * hb0.y + acc[1] * inv;
    o0.z = ONE_MINUS_ALPHA * hb0.z + acc[2] * inv;
    o0.w = ONE_MINUS_ALPHA * hb0.w + acc[3] * inv;
    o1.x = ONE_MINUS_ALPHA * hb1.x + acc[4] * inv;
    o1.y = ONE_MINUS_ALPHA * hb1.y + acc[5] * inv;
    o1.z = ONE_MINUS_ALPHA * hb1.z + acc[6] * inv;
    o1.w = ONE_MINUS_ALPHA * hb1.w + acc[7] * inv;
    *reinterpret_cast<float4*>(h_neigh_out + base)     = o0;
    *reinterpret_cast<float4*>(h_neigh_out + base + 4) = o1;
}

// ---------------------------------------------------------------------------
// Linear kernel: lane = output o; W row o (128 f32) in VGPRs (coalesced fill
// from k-major WT). Waves grid-stride nodes; x-row address wave-uniform
// (readfirstlane) -> x streams through the scalar pipe as s_load broadcasts.
// ---------------------------------------------------------------------------
__global__ __launch_bounds__(256) void sage_linear_kernel(
    const float* __restrict__ H_dst,
    const float* __restrict__ h_neigh,
    const float* __restrict__ WT,        // [128][64] k-major
    const float* __restrict__ b,
    float*       __restrict__ h_out)     // [N_DST][64]
{
    const int lane = threadIdx.x & 63;
    const int wid  = blockIdx.x * 4 + (threadIdx.x >> 6);
    const int nw   = gridDim.x * 4;

    float wreg[128];
    #pragma unroll
    for (int k = 0; k < 128; ++k) wreg[k] = WT[k * 64 + lane];  // coalesced
    const float bias = b[lane];

    for (int node = wid; node < N_DST_C; node += nw) {
        const int un = __builtin_amdgcn_readfirstlane(node);
        const float* __restrict__ xd = H_dst   + (size_t)un * D_C;
        const float* __restrict__ xn = h_neigh + (size_t)un * D_C;

        float a0 = 0.f, a1 = 0.f, a2 = 0.f, a3 = 0.f;
        #pragma unroll
        for (int k = 0; k < 16; ++k) {
            a0 = fmaf(wreg[k * 4 + 0], xd[k * 4 + 0], a0);
            a1 = fmaf(wreg[k * 4 + 1], xd[k * 4 + 1], a1);
            a2 = fmaf(wreg[k * 4 + 2], xd[k * 4 + 2], a2);
            a3 = fmaf(wreg[k * 4 + 3], xd[k * 4 + 3], a3);
        }
        #pragma unroll
        for (int k = 0; k < 16; ++k) {
            a0 = fmaf(wreg[64 + k * 4 + 0], xn[k * 4 + 0], a0);
            a1 = fmaf(wreg[64 + k * 4 + 1], xn[k * 4 + 1], a1);
            a2 = fmaf(wreg[64 + k * 4 + 2], xn[k * 4 + 2], a2);
            a3 = fmaf(wreg[64 + k * 4 + 3], xn[k * 4 + 3], a3);
        }
        h_out[(size_t)un * D_C + lane] = fmaxf(bias + ((a0 + a1) + (a2 + a3)), 0.0f);
    }
}

// ---------------------------------------------------------------------------
extern "C" void kernel_launch(void* const* d_in, const int* in_sizes, int n_in,
                              void* d_out, int out_size, void* d_ws, size_t ws_size,
                              hipStream_t stream) {
    const float* H_src   = (const float*)d_in[0];
    const float* H_dst   = (const float*)d_in[1];
    const float* HBar    = (const float*)d_in[2];
    const int*   src_idx = (const int*)d_in[3];
    const int*   dst_idx = (const int*)d_in[4];
    const float* W       = (const float*)d_in[5];
    const float* b       = (const float*)d_in[6];

    float* out    = (float*)d_out;
    float* h_out  = out;                             // [N_DST][64]
    float* hn_out = out + (size_t)N_DST_C * D_C;     // [N_DST][64]

    // ws layout: row_ptr @0 (200KB), WT @256KB (32KB), Hb @512KB (12.8MB)
    int*    row_ptr = (int*)d_ws;
    float*  WT      = (float*)((char*)d_ws + (256 << 10));
    ushort* Hb      = (ushort*)((char*)d_ws + (512 << 10));

    hipLaunchKernelGGL(prep_kernel, dim3(PREP_BLOCKS), dim3(256), 0, stream,
                       H_src, Hb, dst_idx, row_ptr, W, WT);

    // 8 nodes/wave, 4 waves/block -> 32 nodes/block
    hipLaunchKernelGGL(sage_mean_kernel, dim3((N_DST_C + 31) / 32), dim3(256), 0, stream,
                       Hb, HBar, src_idx, row_ptr, hn_out);

    // 768 blocks = 3072 waves (~3/SIMD at ~140 VGPR), grid-stride over nodes.
    hipLaunchKernelGGL(sage_linear_kernel, dim3(768), dim3(256), 0, stream,
                       H_dst, hn_out, WT, b, h_out);
}